// Round 4
// baseline (1621.014 us; speedup 1.0000x reference)
//
#include <hip/hip_runtime.h>
#include <math.h>

namespace {
constexpr int NN = 100000;   // nodes
constexpr int NE = 1000000;  // edges
constexpr int D  = 64;       // feature dim
constexpr int SCAN_CHUNK = 2048;                 // 256 threads * 8
constexpr int NB = (NN + SCAN_CHUNK - 1) / SCAN_CHUNK;  // 49

__global__ void count_deg_k(const int* __restrict__ rows, int* __restrict__ deg, int e) {
    int i = blockIdx.x * blockDim.x + threadIdx.x;
    if (i < e) atomicAdd(&deg[rows[i]], 1);
}

__global__ void dis_k(const int* __restrict__ deg, float* __restrict__ dis, int n) {
    int i = blockIdx.x * blockDim.x + threadIdx.x;
    if (i < n) dis[i] = rsqrtf((float)(deg[i] + 1));  // +1 self-loop
}

// ---- 3-phase parallel exclusive scan of deg -> rowstart ----
__global__ void scan_partial_k(const int* __restrict__ deg, int* __restrict__ bsum, int n) {
    int base = blockIdx.x * SCAN_CHUNK + threadIdx.x * 8;
    int s = 0;
#pragma unroll
    for (int j = 0; j < 8; ++j) { int i = base + j; s += (i < n) ? deg[i] : 0; }
    for (int off = 32; off; off >>= 1) s += __shfl_down(s, off);
    __shared__ int ws[4];
    if ((threadIdx.x & 63) == 0) ws[threadIdx.x >> 6] = s;
    __syncthreads();
    if (threadIdx.x == 0) bsum[blockIdx.x] = ws[0] + ws[1] + ws[2] + ws[3];
}

__global__ void scan_bsums_k(const int* __restrict__ bsum, int* __restrict__ bpre, int nb) {
    __shared__ int sm[64];
    int v = ((int)threadIdx.x < nb) ? bsum[threadIdx.x] : 0;
    sm[threadIdx.x] = v;
    __syncthreads();
    for (int off = 1; off < 64; off <<= 1) {
        int t = ((int)threadIdx.x >= off) ? sm[threadIdx.x - off] : 0;
        __syncthreads();
        sm[threadIdx.x] += t;
        __syncthreads();
    }
    if ((int)threadIdx.x < nb) bpre[threadIdx.x] = sm[threadIdx.x] - v;  // exclusive
}

__global__ void scan_apply_k(const int* __restrict__ deg, const int* __restrict__ bpre,
                             int* __restrict__ rowstart, int n) {
    int tid = threadIdx.x;
    int base = blockIdx.x * SCAN_CHUNK + tid * 8;
    int v[8]; int s = 0;
#pragma unroll
    for (int j = 0; j < 8; ++j) { int i = base + j; v[j] = (i < n) ? deg[i] : 0; s += v[j]; }
    int lane = tid & 63, wid = tid >> 6;
    int sc = s;
    for (int off = 1; off < 64; off <<= 1) {
        int t = __shfl_up(sc, off);
        if (lane >= off) sc += t;
    }
    __shared__ int wsum[4];
    if (lane == 63) wsum[wid] = sc;
    __syncthreads();
    int wpre = 0;
    for (int w = 0; w < wid; ++w) wpre += wsum[w];
    int run = bpre[blockIdx.x] + wpre + sc - s;  // exclusive prefix of this thread
#pragma unroll
    for (int j = 0; j < 8; ++j) { int i = base + j; if (i < n) rowstart[i] = run; run += v[j]; }
}

// counting-sort edges into row-contiguous segments; pre-resolve dis[c] and perm[c]
__global__ void reorder_k(const int* __restrict__ rows, const int* __restrict__ cols,
                          const int* __restrict__ rowstart, int* __restrict__ cursor,
                          const float* __restrict__ dis, const int* __restrict__ perm,
                          int* __restrict__ scols, int* __restrict__ scolp,
                          float* __restrict__ sdis, int e) {
    int i = blockIdx.x * blockDim.x + threadIdx.x;
    if (i >= e) return;
    int r = rows[i], c = cols[i];
    int pos = rowstart[r] + atomicAdd(&cursor[r], 1);
    scols[pos] = c;
    scolp[pos] = perm[c];
    sdis[pos]  = dis[c];
}

// [n,64] @ [64,64] LDS-tiled, register-blocked. Block = 256 threads (16x16),
// 64 rows/block, 4x4 outputs/thread. x-tile pitch 68 (bank-decorrelated, rows
// 16B-aligned). In-place safe: block reads exactly the rows it writes and all
// global reads precede all stores.
__global__ __launch_bounds__(256, 4)
void gemm64_k(const float* in, const float* __restrict__ W, float* out, int n) {
    __shared__ float sx[64][68];
    __shared__ float sw[64][64];
    int tid = threadIdx.x;
    const float4* W4 = (const float4*)W;
    float4* sw4 = (float4*)&sw[0][0];
#pragma unroll
    for (int i = 0; i < 4; ++i) sw4[tid + 256 * i] = W4[tid + 256 * i];
    int row0 = blockIdx.x * 64;
    const float4* x4 = (const float4*)(in + (size_t)row0 * D);
#pragma unroll
    for (int ii = 0; ii < 4; ++ii) {
        int i = tid + 256 * ii;
        int r = i >> 4, k4 = i & 15;
        float4 v = (row0 + r < n) ? x4[i] : float4{0.f, 0.f, 0.f, 0.f};
        ((float4*)&sx[r][0])[k4] = v;
    }
    __syncthreads();
    int tx = tid & 15, ty = tid >> 4;
    int c0 = tx * 4, r0 = ty * 4;
    float acc[4][4] = {};
#pragma unroll
    for (int kk = 0; kk < 64; kk += 4) {
        float4 b0 = *(const float4*)&sw[kk + 0][c0];
        float4 b1 = *(const float4*)&sw[kk + 1][c0];
        float4 b2 = *(const float4*)&sw[kk + 2][c0];
        float4 b3 = *(const float4*)&sw[kk + 3][c0];
#pragma unroll
        for (int i = 0; i < 4; ++i) {
            float4 a = *(const float4*)&sx[r0 + i][kk];
            acc[i][0] = fmaf(a.x, b0.x, acc[i][0]);
            acc[i][1] = fmaf(a.x, b0.y, acc[i][1]);
            acc[i][2] = fmaf(a.x, b0.z, acc[i][2]);
            acc[i][3] = fmaf(a.x, b0.w, acc[i][3]);
            acc[i][0] = fmaf(a.y, b1.x, acc[i][0]);
            acc[i][1] = fmaf(a.y, b1.y, acc[i][1]);
            acc[i][2] = fmaf(a.y, b1.z, acc[i][2]);
            acc[i][3] = fmaf(a.y, b1.w, acc[i][3]);
            acc[i][0] = fmaf(a.z, b2.x, acc[i][0]);
            acc[i][1] = fmaf(a.z, b2.y, acc[i][1]);
            acc[i][2] = fmaf(a.z, b2.z, acc[i][2]);
            acc[i][3] = fmaf(a.z, b2.w, acc[i][3]);
            acc[i][0] = fmaf(a.w, b3.x, acc[i][0]);
            acc[i][1] = fmaf(a.w, b3.y, acc[i][1]);
            acc[i][2] = fmaf(a.w, b3.z, acc[i][2]);
            acc[i][3] = fmaf(a.w, b3.w, acc[i][3]);
        }
    }
#pragma unroll
    for (int i = 0; i < 4; ++i) {
        int r = row0 + r0 + i;
        if (r < n) {
            float4 v = {acc[i][0], acc[i][1], acc[i][2], acc[i][3]};
            *(float4*)(out + (size_t)r * D + c0) = v;
        }
    }
}

// Dual gather-aggregate: one wave per row, lane = feature, P and N branches in
// one pass (shared index/norm stream, 8 gathers in flight at unroll-4).
__global__ void agg_dual_k(const float* __restrict__ srcP, const float* __restrict__ srcN,
                           float* __restrict__ dstP, float* __restrict__ dstN,
                           const float* __restrict__ dis,
                           const int* __restrict__ rowstart, const int* __restrict__ deg,
                           const int* __restrict__ idxP, const int* __restrict__ idxN,
                           const float* __restrict__ sdis,
                           const float* __restrict__ bias, const float* __restrict__ prelu_a,
                           const int* __restrict__ perm, int n) {
    int lane = threadIdx.x & 63;
    int r = blockIdx.x * (blockDim.x >> 6) + (threadIdx.x >> 6);
    if (r >= n) return;
    int rs   = __builtin_amdgcn_readfirstlane(r);
    int base = __builtin_amdgcn_readfirstlane(rowstart[rs]);
    int dg   = __builtin_amdgcn_readfirstlane(deg[rs]);
    float dr = dis[rs];
    int selfN = perm ? perm[rs] : rs;
    float accP = dr * srcP[(size_t)rs * D + lane];
    float accN = dr * srcN[(size_t)selfN * D + lane];
    int j = 0;
    for (; j + 4 <= dg; j += 4) {
        int   cP0 = idxP[base+j],   cP1 = idxP[base+j+1], cP2 = idxP[base+j+2], cP3 = idxP[base+j+3];
        int   cN0 = idxN[base+j],   cN1 = idxN[base+j+1], cN2 = idxN[base+j+2], cN3 = idxN[base+j+3];
        float n0  = sdis[base+j],   n1  = sdis[base+j+1], n2  = sdis[base+j+2], n3  = sdis[base+j+3];
        float p0 = srcP[(size_t)cP0 * D + lane];
        float p1 = srcP[(size_t)cP1 * D + lane];
        float p2 = srcP[(size_t)cP2 * D + lane];
        float p3 = srcP[(size_t)cP3 * D + lane];
        float q0 = srcN[(size_t)cN0 * D + lane];
        float q1 = srcN[(size_t)cN1 * D + lane];
        float q2 = srcN[(size_t)cN2 * D + lane];
        float q3 = srcN[(size_t)cN3 * D + lane];
        accP = fmaf(n0, p0, accP); accP = fmaf(n1, p1, accP);
        accP = fmaf(n2, p2, accP); accP = fmaf(n3, p3, accP);
        accN = fmaf(n0, q0, accN); accN = fmaf(n1, q1, accN);
        accN = fmaf(n2, q2, accN); accN = fmaf(n3, q3, accN);
    }
    for (; j < dg; ++j) {
        int cP = idxP[base + j], cN = idxN[base + j];
        float nc = sdis[base + j];
        accP = fmaf(nc, srcP[(size_t)cP * D + lane], accP);
        accN = fmaf(nc, srcN[(size_t)cN * D + lane], accN);
    }
    float b = bias[lane];
    float vP = fmaf(dr, accP, b);
    float vN = fmaf(dr, accN, b);
    if (prelu_a) {
        float a = *prelu_a;
        vP = vP >= 0.f ? vP : a * vP;
        vN = vN >= 0.f ? vN : a * vN;
    }
    dstP[(size_t)rs * D + lane] = vP;
    dstN[(size_t)rs * D + lane] = vN;
}

__global__ void summary_partial_k(const float* __restrict__ pos, float* __restrict__ acc, int n) {
    int lane = threadIdx.x & 63;
    int wave = (blockIdx.x * blockDim.x + threadIdx.x) >> 6;
    int nw = (gridDim.x * blockDim.x) >> 6;
    float s = 0.f;
    for (int r = wave; r < n; r += nw) s += pos[(size_t)r * D + lane];
    atomicAdd(&acc[lane], s);
}

__global__ void summary_final_k(const float* __restrict__ acc, float* __restrict__ out, int n) {
    int f = threadIdx.x;
    if (f < D) {
        float m = acc[f] / (float)n;
        out[f] = 1.f / (1.f + expf(-m));
    }
}
} // namespace

extern "C" void kernel_launch(void* const* d_in, const int* in_sizes, int n_in,
                              void* d_out, int out_size, void* d_ws, size_t ws_size,
                              hipStream_t stream) {
    (void)in_sizes; (void)n_in; (void)out_size; (void)ws_size;
    const float* x       = (const float*)d_in[0];
    const int*   ei      = (const int*)  d_in[1];
    const int*   perm    = (const int*)  d_in[2];
    const float* W1      = (const float*)d_in[3];
    const float* b1      = (const float*)d_in[4];
    const float* prelu_a = (const float*)d_in[5];
    const float* W2      = (const float*)d_in[6];
    const float* b2      = (const float*)d_in[7];

    float* outP = (float*)d_out;
    float* outN = outP + (size_t)NN * D;
    float* outS = outN + (size_t)NN * D;

    const int* erows = ei;
    const int* ecols = ei + NE;

    char* ws = (char*)d_ws;
    size_t off = 0;
    auto alloc = [&](size_t bytes) {
        void* p = ws + off;
        off = (off + bytes + 255) & ~(size_t)255;
        return p;
    };
    int*   deg      = (int*)  alloc((size_t)NN * 4);
    float* dis      = (float*)alloc((size_t)NN * 4);
    int*   rowstart = (int*)  alloc((size_t)NN * 4);
    int*   cursor   = (int*)  alloc((size_t)NN * 4);
    int*   bsum     = (int*)  alloc(256);
    int*   bpre     = (int*)  alloc(256);
    int*   scols    = (int*)  alloc((size_t)NE * 4);
    int*   scolp    = (int*)  alloc((size_t)NE * 4);
    float* sdis     = (float*)alloc((size_t)NE * 4);
    float* xw       = (float*)alloc((size_t)NN * D * 4);
    float* aggP     = (float*)alloc((size_t)NN * D * 4);
    float* aggN     = (float*)alloc((size_t)NN * D * 4);
    float* acc      = (float*)alloc((size_t)D * 4);

    hipMemsetAsync(deg, 0, (size_t)NN * 4, stream);
    hipMemsetAsync(cursor, 0, (size_t)NN * 4, stream);
    hipMemsetAsync(acc, 0, (size_t)D * 4, stream);

    // graph preprocessing (reused by both layers and both branches)
    count_deg_k<<<(NE + 255) / 256, 256, 0, stream>>>(erows, deg, NE);
    dis_k<<<(NN + 255) / 256, 256, 0, stream>>>(deg, dis, NN);
    scan_partial_k<<<NB, 256, 0, stream>>>(deg, bsum, NN);
    scan_bsums_k<<<1, 64, 0, stream>>>(bsum, bpre, NB);
    scan_apply_k<<<NB, 256, 0, stream>>>(deg, bpre, rowstart, NN);
    reorder_k<<<(NE + 255) / 256, 256, 0, stream>>>(erows, ecols, rowstart, cursor,
                                                    dis, perm, scols, scolp, sdis, NE);

    const int gemmBlocks = (NN + 63) / 64;
    const int aggBlocks  = (NN + 3) / 4;

    // layer 1: xw = x@W1 once; N branch = permuted gather from same table
    gemm64_k<<<gemmBlocks, 256, 0, stream>>>(x, W1, xw, NN);
    agg_dual_k<<<aggBlocks, 256, 0, stream>>>(xw, xw, aggP, aggN, dis, rowstart, deg,
                                              scols, scolp, sdis, b1, prelu_a, perm, NN);

    // layer 2: in-place gemms, then dual aggregate with shared index stream
    gemm64_k<<<gemmBlocks, 256, 0, stream>>>(aggP, W2, aggP, NN);
    gemm64_k<<<gemmBlocks, 256, 0, stream>>>(aggN, W2, aggN, NN);
    agg_dual_k<<<aggBlocks, 256, 0, stream>>>(aggP, aggN, outP, outN, dis, rowstart, deg,
                                              scols, scols, sdis, b2, nullptr, nullptr, NN);

    // summary = sigmoid(mean(positive, axis=0))
    summary_partial_k<<<256, 256, 0, stream>>>(outP, acc, NN);
    summary_final_k<<<1, 64, 0, stream>>>(acc, outS, NN);
}

// Round 5
// 457.138 us; speedup vs baseline: 3.5460x; 3.5460x over previous
//
#include <hip/hip_runtime.h>
#include <math.h>

namespace {
constexpr int NN = 100000;   // nodes
constexpr int NE = 1000000;  // edges
constexpr int D  = 64;       // feature dim
constexpr int SCAN_CHUNK = 2048;                 // 256 threads * 8
constexpr int NB = (NN + SCAN_CHUNK - 1) / SCAN_CHUNK;  // 49

__global__ void count_deg_k(const int* __restrict__ rows, int* __restrict__ deg, int e) {
    int i = blockIdx.x * blockDim.x + threadIdx.x;
    if (i < e) atomicAdd(&deg[rows[i]], 1);
}

__global__ void dis_k(const int* __restrict__ deg, float* __restrict__ dis, int n) {
    int i = blockIdx.x * blockDim.x + threadIdx.x;
    if (i < n) dis[i] = rsqrtf((float)(deg[i] + 1));  // +1 self-loop
}

// ---- 3-phase parallel exclusive scan of deg -> rowstart ----
__global__ void scan_partial_k(const int* __restrict__ deg, int* __restrict__ bsum, int n) {
    int base = blockIdx.x * SCAN_CHUNK + threadIdx.x * 8;
    int s = 0;
#pragma unroll
    for (int j = 0; j < 8; ++j) { int i = base + j; s += (i < n) ? deg[i] : 0; }
    for (int off = 32; off; off >>= 1) s += __shfl_down(s, off);
    __shared__ int ws[4];
    if ((threadIdx.x & 63) == 0) ws[threadIdx.x >> 6] = s;
    __syncthreads();
    if (threadIdx.x == 0) bsum[blockIdx.x] = ws[0] + ws[1] + ws[2] + ws[3];
}

__global__ void scan_bsums_k(const int* __restrict__ bsum, int* __restrict__ bpre, int nb) {
    __shared__ int sm[64];
    int v = ((int)threadIdx.x < nb) ? bsum[threadIdx.x] : 0;
    sm[threadIdx.x] = v;
    __syncthreads();
    for (int off = 1; off < 64; off <<= 1) {
        int t = ((int)threadIdx.x >= off) ? sm[threadIdx.x - off] : 0;
        __syncthreads();
        sm[threadIdx.x] += t;
        __syncthreads();
    }
    if ((int)threadIdx.x < nb) bpre[threadIdx.x] = sm[threadIdx.x] - v;  // exclusive
}

__global__ void scan_apply_k(const int* __restrict__ deg, const int* __restrict__ bpre,
                             int* __restrict__ rowstart, int n) {
    int tid = threadIdx.x;
    int base = blockIdx.x * SCAN_CHUNK + tid * 8;
    int v[8]; int s = 0;
#pragma unroll
    for (int j = 0; j < 8; ++j) { int i = base + j; v[j] = (i < n) ? deg[i] : 0; s += v[j]; }
    int lane = tid & 63, wid = tid >> 6;
    int sc = s;
    for (int off = 1; off < 64; off <<= 1) {
        int t = __shfl_up(sc, off);
        if (lane >= off) sc += t;
    }
    __shared__ int wsum[4];
    if (lane == 63) wsum[wid] = sc;
    __syncthreads();
    int wpre = 0;
    for (int w = 0; w < wid; ++w) wpre += wsum[w];
    int run = bpre[blockIdx.x] + wpre + sc - s;  // exclusive prefix of this thread
#pragma unroll
    for (int j = 0; j < 8; ++j) { int i = base + j; if (i < n) rowstart[i] = run; run += v[j]; }
}

// counting-sort edges into row-contiguous segments; pre-resolve dis[c] and perm[c]
__global__ void reorder_k(const int* __restrict__ rows, const int* __restrict__ cols,
                          const int* __restrict__ rowstart, int* __restrict__ cursor,
                          const float* __restrict__ dis, const int* __restrict__ perm,
                          int* __restrict__ scols, int* __restrict__ scolp,
                          float* __restrict__ sdis, int e) {
    int i = blockIdx.x * blockDim.x + threadIdx.x;
    if (i >= e) return;
    int r = rows[i], c = cols[i];
    int pos = rowstart[r] + atomicAdd(&cursor[r], 1);
    scols[pos] = c;
    scolp[pos] = perm[c];
    sdis[pos]  = dis[c];
}

// [n,64] @ [64,64] LDS-tiled, register-blocked. Block = 256 threads (16x16),
// 64 rows/block, 4x4 outputs/thread. NO __launch_bounds__: a 64-VGPR cap
// makes the unrolled inner loop spill accumulators to scratch (round-4
// regression: +600 MB HBM spill traffic). Let allocator take ~128 VGPRs.
// In-place safe: block reads exactly the rows it writes; per-thread ordering
// guarantees loads before stores; no cross-block row sharing.
__global__ void gemm64_k(const float* in, const float* __restrict__ W, float* out, int n) {
    __shared__ float sx[64][68];
    __shared__ float sw[64][64];
    int tid = threadIdx.x;
    const float4* W4 = (const float4*)W;
    float4* sw4 = (float4*)&sw[0][0];
#pragma unroll
    for (int i = 0; i < 4; ++i) sw4[tid + 256 * i] = W4[tid + 256 * i];
    int row0 = blockIdx.x * 64;
    const float4* x4 = (const float4*)(in + (size_t)row0 * D);
#pragma unroll
    for (int ii = 0; ii < 4; ++ii) {
        int i = tid + 256 * ii;
        int r = i >> 4, k4 = i & 15;
        float4 v = (row0 + r < n) ? x4[i] : float4{0.f, 0.f, 0.f, 0.f};
        ((float4*)&sx[r][0])[k4] = v;
    }
    __syncthreads();
    int tx = tid & 15, ty = tid >> 4;
    int c0 = tx * 4, r0 = ty * 4;
    float acc[4][4] = {};
#pragma unroll 4
    for (int kk = 0; kk < 64; kk += 4) {
        float4 b0 = *(const float4*)&sw[kk + 0][c0];
        float4 b1 = *(const float4*)&sw[kk + 1][c0];
        float4 b2 = *(const float4*)&sw[kk + 2][c0];
        float4 b3 = *(const float4*)&sw[kk + 3][c0];
#pragma unroll
        for (int i = 0; i < 4; ++i) {
            float4 a = *(const float4*)&sx[r0 + i][kk];
            acc[i][0] = fmaf(a.x, b0.x, acc[i][0]);
            acc[i][1] = fmaf(a.x, b0.y, acc[i][1]);
            acc[i][2] = fmaf(a.x, b0.z, acc[i][2]);
            acc[i][3] = fmaf(a.x, b0.w, acc[i][3]);
            acc[i][0] = fmaf(a.y, b1.x, acc[i][0]);
            acc[i][1] = fmaf(a.y, b1.y, acc[i][1]);
            acc[i][2] = fmaf(a.y, b1.z, acc[i][2]);
            acc[i][3] = fmaf(a.y, b1.w, acc[i][3]);
            acc[i][0] = fmaf(a.z, b2.x, acc[i][0]);
            acc[i][1] = fmaf(a.z, b2.y, acc[i][1]);
            acc[i][2] = fmaf(a.z, b2.z, acc[i][2]);
            acc[i][3] = fmaf(a.z, b2.w, acc[i][3]);
            acc[i][0] = fmaf(a.w, b3.x, acc[i][0]);
            acc[i][1] = fmaf(a.w, b3.y, acc[i][1]);
            acc[i][2] = fmaf(a.w, b3.z, acc[i][2]);
            acc[i][3] = fmaf(a.w, b3.w, acc[i][3]);
        }
    }
#pragma unroll
    for (int i = 0; i < 4; ++i) {
        int r = row0 + r0 + i;
        if (r < n) {
            float4 v = {acc[i][0], acc[i][1], acc[i][2], acc[i][3]};
            *(float4*)(out + (size_t)r * D + c0) = v;
        }
    }
}

// Dual gather-aggregate: one wave per row, lane = feature, P and N branches in
// one pass (shared index/norm stream, 8 gathers in flight at unroll-4).
__global__ void agg_dual_k(const float* __restrict__ srcP, const float* __restrict__ srcN,
                           float* __restrict__ dstP, float* __restrict__ dstN,
                           const float* __restrict__ dis,
                           const int* __restrict__ rowstart, const int* __restrict__ deg,
                           const int* __restrict__ idxP, const int* __restrict__ idxN,
                           const float* __restrict__ sdis,
                           const float* __restrict__ bias, const float* __restrict__ prelu_a,
                           const int* __restrict__ perm, int n) {
    int lane = threadIdx.x & 63;
    int r = blockIdx.x * (blockDim.x >> 6) + (threadIdx.x >> 6);
    if (r >= n) return;
    int rs   = __builtin_amdgcn_readfirstlane(r);
    int base = __builtin_amdgcn_readfirstlane(rowstart[rs]);
    int dg   = __builtin_amdgcn_readfirstlane(deg[rs]);
    float dr = dis[rs];
    int selfN = perm ? perm[rs] : rs;
    float accP = dr * srcP[(size_t)rs * D + lane];
    float accN = dr * srcN[(size_t)selfN * D + lane];
    int j = 0;
    for (; j + 4 <= dg; j += 4) {
        int   cP0 = idxP[base+j],   cP1 = idxP[base+j+1], cP2 = idxP[base+j+2], cP3 = idxP[base+j+3];
        int   cN0 = idxN[base+j],   cN1 = idxN[base+j+1], cN2 = idxN[base+j+2], cN3 = idxN[base+j+3];
        float n0  = sdis[base+j],   n1  = sdis[base+j+1], n2  = sdis[base+j+2], n3  = sdis[base+j+3];
        float p0 = srcP[(size_t)cP0 * D + lane];
        float p1 = srcP[(size_t)cP1 * D + lane];
        float p2 = srcP[(size_t)cP2 * D + lane];
        float p3 = srcP[(size_t)cP3 * D + lane];
        float q0 = srcN[(size_t)cN0 * D + lane];
        float q1 = srcN[(size_t)cN1 * D + lane];
        float q2 = srcN[(size_t)cN2 * D + lane];
        float q3 = srcN[(size_t)cN3 * D + lane];
        accP = fmaf(n0, p0, accP); accP = fmaf(n1, p1, accP);
        accP = fmaf(n2, p2, accP); accP = fmaf(n3, p3, accP);
        accN = fmaf(n0, q0, accN); accN = fmaf(n1, q1, accN);
        accN = fmaf(n2, q2, accN); accN = fmaf(n3, q3, accN);
    }
    for (; j < dg; ++j) {
        int cP = idxP[base + j], cN = idxN[base + j];
        float nc = sdis[base + j];
        accP = fmaf(nc, srcP[(size_t)cP * D + lane], accP);
        accN = fmaf(nc, srcN[(size_t)cN * D + lane], accN);
    }
    float b = bias[lane];
    float vP = fmaf(dr, accP, b);
    float vN = fmaf(dr, accN, b);
    if (prelu_a) {
        float a = *prelu_a;
        vP = vP >= 0.f ? vP : a * vP;
        vN = vN >= 0.f ? vN : a * vN;
    }
    dstP[(size_t)rs * D + lane] = vP;
    dstN[(size_t)rs * D + lane] = vN;
}

__global__ void summary_partial_k(const float* __restrict__ pos, float* __restrict__ acc, int n) {
    int lane = threadIdx.x & 63;
    int wave = (blockIdx.x * blockDim.x + threadIdx.x) >> 6;
    int nw = (gridDim.x * blockDim.x) >> 6;
    float s = 0.f;
    for (int r = wave; r < n; r += nw) s += pos[(size_t)r * D + lane];
    atomicAdd(&acc[lane], s);
}

__global__ void summary_final_k(const float* __restrict__ acc, float* __restrict__ out, int n) {
    int f = threadIdx.x;
    if (f < D) {
        float m = acc[f] / (float)n;
        out[f] = 1.f / (1.f + expf(-m));
    }
}
} // namespace

extern "C" void kernel_launch(void* const* d_in, const int* in_sizes, int n_in,
                              void* d_out, int out_size, void* d_ws, size_t ws_size,
                              hipStream_t stream) {
    (void)in_sizes; (void)n_in; (void)out_size; (void)ws_size;
    const float* x       = (const float*)d_in[0];
    const int*   ei      = (const int*)  d_in[1];
    const int*   perm    = (const int*)  d_in[2];
    const float* W1      = (const float*)d_in[3];
    const float* b1      = (const float*)d_in[4];
    const float* prelu_a = (const float*)d_in[5];
    const float* W2      = (const float*)d_in[6];
    const float* b2      = (const float*)d_in[7];

    float* outP = (float*)d_out;
    float* outN = outP + (size_t)NN * D;
    float* outS = outN + (size_t)NN * D;

    const int* erows = ei;
    const int* ecols = ei + NE;

    char* ws = (char*)d_ws;
    size_t off = 0;
    auto alloc = [&](size_t bytes) {
        void* p = ws + off;
        off = (off + bytes + 255) & ~(size_t)255;
        return p;
    };
    int*   deg      = (int*)  alloc((size_t)NN * 4);
    float* dis      = (float*)alloc((size_t)NN * 4);
    int*   rowstart = (int*)  alloc((size_t)NN * 4);
    int*   cursor   = (int*)  alloc((size_t)NN * 4);
    int*   bsum     = (int*)  alloc(256);
    int*   bpre     = (int*)  alloc(256);
    int*   scols    = (int*)  alloc((size_t)NE * 4);
    int*   scolp    = (int*)  alloc((size_t)NE * 4);
    float* sdis     = (float*)alloc((size_t)NE * 4);
    float* xw       = (float*)alloc((size_t)NN * D * 4);
    float* aggP     = (float*)alloc((size_t)NN * D * 4);
    float* aggN     = (float*)alloc((size_t)NN * D * 4);
    float* acc      = (float*)alloc((size_t)D * 4);

    hipMemsetAsync(deg, 0, (size_t)NN * 4, stream);
    hipMemsetAsync(cursor, 0, (size_t)NN * 4, stream);
    hipMemsetAsync(acc, 0, (size_t)D * 4, stream);

    // graph preprocessing (reused by both layers and both branches)
    count_deg_k<<<(NE + 255) / 256, 256, 0, stream>>>(erows, deg, NE);
    dis_k<<<(NN + 255) / 256, 256, 0, stream>>>(deg, dis, NN);
    scan_partial_k<<<NB, 256, 0, stream>>>(deg, bsum, NN);
    scan_bsums_k<<<1, 64, 0, stream>>>(bsum, bpre, NB);
    scan_apply_k<<<NB, 256, 0, stream>>>(deg, bpre, rowstart, NN);
    reorder_k<<<(NE + 255) / 256, 256, 0, stream>>>(erows, ecols, rowstart, cursor,
                                                    dis, perm, scols, scolp, sdis, NE);

    const int gemmBlocks = (NN + 63) / 64;
    const int aggBlocks  = (NN + 3) / 4;

    // layer 1: xw = x@W1 once; N branch = permuted gather from same table
    gemm64_k<<<gemmBlocks, 256, 0, stream>>>(x, W1, xw, NN);
    agg_dual_k<<<aggBlocks, 256, 0, stream>>>(xw, xw, aggP, aggN, dis, rowstart, deg,
                                              scols, scolp, sdis, b1, prelu_a, perm, NN);

    // layer 2: in-place gemms, then dual aggregate with shared index stream
    gemm64_k<<<gemmBlocks, 256, 0, stream>>>(aggP, W2, aggP, NN);
    gemm64_k<<<gemmBlocks, 256, 0, stream>>>(aggN, W2, aggN, NN);
    agg_dual_k<<<aggBlocks, 256, 0, stream>>>(aggP, aggN, outP, outN, dis, rowstart, deg,
                                              scols, scols, sdis, b2, nullptr, nullptr, NN);

    // summary = sigmoid(mean(positive, axis=0))
    summary_partial_k<<<256, 256, 0, stream>>>(outP, acc, NN);
    summary_final_k<<<1, 64, 0, stream>>>(acc, outS, NN);
}

// Round 6
// 404.834 us; speedup vs baseline: 4.0041x; 1.1292x over previous
//
#include <hip/hip_runtime.h>
#include <math.h>

namespace {
constexpr int NN = 100000;   // nodes
constexpr int NE = 1000000;  // edges
constexpr int D  = 64;       // feature dim
constexpr int SCAN_CHUNK = 2048;                 // 256 threads * 8
constexpr int NB = (NN + SCAN_CHUNK - 1) / SCAN_CHUNK;  // 49

using ushort_t = unsigned short;

__device__ inline float bf2f(ushort_t u) {
    return __uint_as_float(((unsigned int)u) << 16);
}
__device__ inline ushort_t f2bf(float f) {   // round-to-nearest-even
    unsigned int x = __float_as_uint(f);
    unsigned int r = (x + 0x7fffu + ((x >> 16) & 1u)) >> 16;
    return (ushort_t)r;
}

__global__ void count_deg_k(const int* __restrict__ rows, int* __restrict__ deg, int e) {
    int i = blockIdx.x * blockDim.x + threadIdx.x;
    if (i < e) atomicAdd(&deg[rows[i]], 1);
}

// ---- 3-phase parallel exclusive scan of deg -> rowstart (dis fused in apply) ----
__global__ void scan_partial_k(const int* __restrict__ deg, int* __restrict__ bsum, int n) {
    int base = blockIdx.x * SCAN_CHUNK + threadIdx.x * 8;
    int s = 0;
#pragma unroll
    for (int j = 0; j < 8; ++j) { int i = base + j; s += (i < n) ? deg[i] : 0; }
    for (int off = 32; off; off >>= 1) s += __shfl_down(s, off);
    __shared__ int ws[4];
    if ((threadIdx.x & 63) == 0) ws[threadIdx.x >> 6] = s;
    __syncthreads();
    if (threadIdx.x == 0) bsum[blockIdx.x] = ws[0] + ws[1] + ws[2] + ws[3];
}

__global__ void scan_bsums_k(const int* __restrict__ bsum, int* __restrict__ bpre, int nb) {
    __shared__ int sm[64];
    int v = ((int)threadIdx.x < nb) ? bsum[threadIdx.x] : 0;
    sm[threadIdx.x] = v;
    __syncthreads();
    for (int off = 1; off < 64; off <<= 1) {
        int t = ((int)threadIdx.x >= off) ? sm[threadIdx.x - off] : 0;
        __syncthreads();
        sm[threadIdx.x] += t;
        __syncthreads();
    }
    if ((int)threadIdx.x < nb) bpre[threadIdx.x] = sm[threadIdx.x] - v;  // exclusive
}

__global__ void scan_apply_k(const int* __restrict__ deg, const int* __restrict__ bpre,
                             int* __restrict__ rowstart, float* __restrict__ dis, int n) {
    int tid = threadIdx.x;
    int base = blockIdx.x * SCAN_CHUNK + tid * 8;
    int v[8]; int s = 0;
#pragma unroll
    for (int j = 0; j < 8; ++j) { int i = base + j; v[j] = (i < n) ? deg[i] : 0; s += v[j]; }
    int lane = tid & 63, wid = tid >> 6;
    int sc = s;
    for (int off = 1; off < 64; off <<= 1) {
        int t = __shfl_up(sc, off);
        if (lane >= off) sc += t;
    }
    __shared__ int wsum[4];
    if (lane == 63) wsum[wid] = sc;
    __syncthreads();
    int wpre = 0;
    for (int w = 0; w < wid; ++w) wpre += wsum[w];
    int run = bpre[blockIdx.x] + wpre + sc - s;  // exclusive prefix of this thread
#pragma unroll
    for (int j = 0; j < 8; ++j) {
        int i = base + j;
        if (i < n) {
            rowstart[i] = run;
            dis[i] = rsqrtf((float)(v[j] + 1));  // +1 self-loop
        }
        run += v[j];
    }
}

// counting-sort edges into row-contiguous segments (index only — norms folded
// into the bf16 gather tables, permutation folded into the pxs table)
__global__ void reorder_k(const int* __restrict__ rows, const int* __restrict__ cols,
                          const int* __restrict__ rowstart, int* __restrict__ cursor,
                          int* __restrict__ scols, int e) {
    int i = blockIdx.x * blockDim.x + threadIdx.x;
    if (i >= e) return;
    int r = rows[i], c = cols[i];
    int pos = rowstart[r] + atomicAdd(&cursor[r], 1);
    scols[pos] = c;
}

// [n,64] @ [64,64] LDS-tiled, register-blocked. 256 thr (16x16), 64 rows/block,
// 4x4 out/thread. NO __launch_bounds__ (64-VGPR cap => accumulator spill, R4).
// Epilogue: outS[r] = bf16(dis[rm]*acc) (scaled gather table); optionally
// outU[r] = bf16(acc) (unscaled, for building the permuted table).
__global__ void gemm64_k(const float* __restrict__ in, const float* __restrict__ W,
                         ushort_t* __restrict__ outS, ushort_t* outU,
                         const float* __restrict__ dis, int n, int nmod) {
    __shared__ float sx[64][68];
    __shared__ float sw[64][64];
    int tid = threadIdx.x;
    const float4* W4 = (const float4*)W;
    float4* sw4 = (float4*)&sw[0][0];
#pragma unroll
    for (int i = 0; i < 4; ++i) sw4[tid + 256 * i] = W4[tid + 256 * i];
    int row0 = blockIdx.x * 64;
    const float4* x4 = (const float4*)(in + (size_t)row0 * D);
#pragma unroll
    for (int ii = 0; ii < 4; ++ii) {
        int i = tid + 256 * ii;
        int r = i >> 4, k4 = i & 15;
        float4 v = (row0 + r < n) ? x4[i] : float4{0.f, 0.f, 0.f, 0.f};
        ((float4*)&sx[r][0])[k4] = v;
    }
    __syncthreads();
    int tx = tid & 15, ty = tid >> 4;
    int c0 = tx * 4, r0 = ty * 4;
    float acc[4][4] = {};
#pragma unroll 4
    for (int kk = 0; kk < 64; kk += 4) {
        float4 b0 = *(const float4*)&sw[kk + 0][c0];
        float4 b1 = *(const float4*)&sw[kk + 1][c0];
        float4 b2 = *(const float4*)&sw[kk + 2][c0];
        float4 b3 = *(const float4*)&sw[kk + 3][c0];
#pragma unroll
        for (int i = 0; i < 4; ++i) {
            float4 a = *(const float4*)&sx[r0 + i][kk];
            acc[i][0] = fmaf(a.x, b0.x, acc[i][0]);
            acc[i][1] = fmaf(a.x, b0.y, acc[i][1]);
            acc[i][2] = fmaf(a.x, b0.z, acc[i][2]);
            acc[i][3] = fmaf(a.x, b0.w, acc[i][3]);
            acc[i][0] = fmaf(a.y, b1.x, acc[i][0]);
            acc[i][1] = fmaf(a.y, b1.y, acc[i][1]);
            acc[i][2] = fmaf(a.y, b1.z, acc[i][2]);
            acc[i][3] = fmaf(a.y, b1.w, acc[i][3]);
            acc[i][0] = fmaf(a.z, b2.x, acc[i][0]);
            acc[i][1] = fmaf(a.z, b2.y, acc[i][1]);
            acc[i][2] = fmaf(a.z, b2.z, acc[i][2]);
            acc[i][3] = fmaf(a.z, b2.w, acc[i][3]);
            acc[i][0] = fmaf(a.w, b3.x, acc[i][0]);
            acc[i][1] = fmaf(a.w, b3.y, acc[i][1]);
            acc[i][2] = fmaf(a.w, b3.z, acc[i][2]);
            acc[i][3] = fmaf(a.w, b3.w, acc[i][3]);
        }
    }
#pragma unroll
    for (int i = 0; i < 4; ++i) {
        int r = row0 + r0 + i;
        if (r < n) {
            int rm = (r >= nmod) ? r - nmod : r;
            float s = dis[rm];
            ushort_t u0[4], u1[4];
#pragma unroll
            for (int j = 0; j < 4; ++j) {
                u0[j] = f2bf(s * acc[i][j]);
                u1[j] = f2bf(acc[i][j]);
            }
            *(uint2*)(outS + (size_t)r * D + c0) = *(uint2*)u0;  // 8B store
            if (outU) *(uint2*)(outU + (size_t)r * D + c0) = *(uint2*)u1;
        }
    }
}

// pxs[r] = dis[r] * xw[perm[r]] — permuted, scaled gather table (bf16)
__global__ void build_perm_k(const ushort_t* __restrict__ xw_bf,
                             ushort_t* __restrict__ pxs,
                             const int* __restrict__ perm,
                             const float* __restrict__ dis, int n) {
    int lane = threadIdx.x & 63;
    int r = blockIdx.x * (blockDim.x >> 6) + (threadIdx.x >> 6);
    if (r >= n) return;
    int pr = perm[r];
    float s = dis[r];
    pxs[(size_t)r * D + lane] = f2bf(s * bf2f(xw_bf[(size_t)pr * D + lane]));
}

// Dual gather-aggregate: one wave per row, lane = feature, P and N branches
// share ONE index stream; norms pre-folded into bf16 tables.
// outX[r] = dis[r]*(sum_j tX[c_j] + tX[r]) + b  (+ optional PReLU)
__global__ void agg_dual_k(const ushort_t* __restrict__ tP, const ushort_t* __restrict__ tN,
                           float* __restrict__ dstP, float* __restrict__ dstN,
                           const float* __restrict__ dis,
                           const int* __restrict__ rowstart, const int* __restrict__ deg,
                           const int* __restrict__ scols,
                           const float* __restrict__ bias, const float* __restrict__ prelu_a,
                           int n) {
    int lane = threadIdx.x & 63;
    int r = blockIdx.x * (blockDim.x >> 6) + (threadIdx.x >> 6);
    if (r >= n) return;
    int rs   = __builtin_amdgcn_readfirstlane(r);
    int base = __builtin_amdgcn_readfirstlane(rowstart[rs]);
    int dg   = __builtin_amdgcn_readfirstlane(deg[rs]);
    float dr = dis[rs];
    float accP = bf2f(tP[(size_t)rs * D + lane]);   // self-loop term
    float accN = bf2f(tN[(size_t)rs * D + lane]);
    int j = 0;
    for (; j + 4 <= dg; j += 4) {
        int c0 = scols[base + j],     c1 = scols[base + j + 1];
        int c2 = scols[base + j + 2], c3 = scols[base + j + 3];
        float p0 = bf2f(tP[(size_t)c0 * D + lane]);
        float p1 = bf2f(tP[(size_t)c1 * D + lane]);
        float p2 = bf2f(tP[(size_t)c2 * D + lane]);
        float p3 = bf2f(tP[(size_t)c3 * D + lane]);
        float q0 = bf2f(tN[(size_t)c0 * D + lane]);
        float q1 = bf2f(tN[(size_t)c1 * D + lane]);
        float q2 = bf2f(tN[(size_t)c2 * D + lane]);
        float q3 = bf2f(tN[(size_t)c3 * D + lane]);
        accP += (p0 + p1) + (p2 + p3);
        accN += (q0 + q1) + (q2 + q3);
    }
    for (; j < dg; ++j) {
        int c = scols[base + j];
        accP += bf2f(tP[(size_t)c * D + lane]);
        accN += bf2f(tN[(size_t)c * D + lane]);
    }
    float b = bias[lane];
    float vP = fmaf(dr, accP, b);
    float vN = fmaf(dr, accN, b);
    if (prelu_a) {
        float a = *prelu_a;
        vP = vP >= 0.f ? vP : a * vP;
        vN = vN >= 0.f ? vN : a * vN;
    }
    dstP[(size_t)rs * D + lane] = vP;
    dstN[(size_t)rs * D + lane] = vN;
}

__global__ void summary_partial_k(const float* __restrict__ pos, float* __restrict__ acc, int n) {
    int lane = threadIdx.x & 63;
    int wave = (blockIdx.x * blockDim.x + threadIdx.x) >> 6;
    int nw = (gridDim.x * blockDim.x) >> 6;
    float s = 0.f;
    for (int r = wave; r < n; r += nw) s += pos[(size_t)r * D + lane];
    atomicAdd(&acc[lane], s);
}

__global__ void summary_final_k(const float* __restrict__ acc, float* __restrict__ out, int n) {
    int f = threadIdx.x;
    if (f < D) {
        float m = acc[f] / (float)n;
        out[f] = 1.f / (1.f + expf(-m));
    }
}
} // namespace

extern "C" void kernel_launch(void* const* d_in, const int* in_sizes, int n_in,
                              void* d_out, int out_size, void* d_ws, size_t ws_size,
                              hipStream_t stream) {
    (void)in_sizes; (void)n_in; (void)out_size; (void)ws_size;
    const float* x       = (const float*)d_in[0];
    const int*   ei      = (const int*)  d_in[1];
    const int*   perm    = (const int*)  d_in[2];
    const float* W1      = (const float*)d_in[3];
    const float* b1      = (const float*)d_in[4];
    const float* prelu_a = (const float*)d_in[5];
    const float* W2      = (const float*)d_in[6];
    const float* b2      = (const float*)d_in[7];

    float* outP = (float*)d_out;
    float* outN = outP + (size_t)NN * D;
    float* outS = outN + (size_t)NN * D;

    const int* erows = ei;
    const int* ecols = ei + NE;

    char* ws = (char*)d_ws;
    size_t off = 0;
    auto alloc = [&](size_t bytes) {
        void* p = ws + off;
        off = (off + bytes + 255) & ~(size_t)255;
        return p;
    };
    int*      deg      = (int*)     alloc((size_t)NN * 4);
    float*    dis      = (float*)   alloc((size_t)NN * 4);
    int*      rowstart = (int*)     alloc((size_t)NN * 4);
    int*      cursor   = (int*)     alloc((size_t)NN * 4);
    int*      bsum     = (int*)     alloc(256);
    int*      bpre     = (int*)     alloc(256);
    int*      scols    = (int*)     alloc((size_t)NE * 4);
    ushort_t* xs       = (ushort_t*)alloc((size_t)NN * D * 2);   // dis-scaled x@W1 (bf16)
    ushort_t* xw_bf    = (ushort_t*)alloc((size_t)NN * D * 2);   // unscaled x@W1 (bf16)
    float*    aggP     = (float*)   alloc((size_t)2 * NN * D * 4); // [aggP | aggN] contiguous
    float*    aggN     = aggP + (size_t)NN * D;
    ushort_t* tP       = (ushort_t*)alloc((size_t)2 * NN * D * 2); // [tP | tN] contiguous (L2 tables)
    ushort_t* tN       = tP + (size_t)NN * D;
    ushort_t* pxs      = tN;    // alias: permuted L1 table lives where tN goes later
    float*    acc      = (float*)   alloc((size_t)D * 4);
    // ~96 MB total

    hipMemsetAsync(deg, 0, (size_t)NN * 4, stream);
    hipMemsetAsync(cursor, 0, (size_t)NN * 4, stream);
    hipMemsetAsync(acc, 0, (size_t)D * 4, stream);

    // graph preprocessing (reused by both layers and both branches)
    count_deg_k<<<(NE + 255) / 256, 256, 0, stream>>>(erows, deg, NE);
    scan_partial_k<<<NB, 256, 0, stream>>>(deg, bsum, NN);
    scan_bsums_k<<<1, 64, 0, stream>>>(bsum, bpre, NB);
    scan_apply_k<<<NB, 256, 0, stream>>>(deg, bpre, rowstart, dis, NN);
    reorder_k<<<(NE + 255) / 256, 256, 0, stream>>>(erows, ecols, rowstart, cursor, scols, NE);

    const int aggBlocks = (NN + 3) / 4;

    // layer 1: xs = dis*x@W1 (bf16), xw_bf = x@W1 (bf16); pxs = permuted+scaled
    gemm64_k<<<(NN + 63) / 64, 256, 0, stream>>>(x, W1, xs, xw_bf, dis, NN, NN);
    build_perm_k<<<aggBlocks, 256, 0, stream>>>(xw_bf, pxs, perm, dis, NN);
    agg_dual_k<<<aggBlocks, 256, 0, stream>>>(xs, pxs, aggP, aggN, dis, rowstart, deg,
                                              scols, b1, prelu_a, NN);

    // layer 2: one gemm over [aggP|aggN] (200k rows) -> scaled bf16 tables
    gemm64_k<<<(2 * NN + 63) / 64, 256, 0, stream>>>(aggP, W2, tP, nullptr, dis, 2 * NN, NN);
    agg_dual_k<<<aggBlocks, 256, 0, stream>>>(tP, tN, outP, outN, dis, rowstart, deg,
                                              scols, b2, nullptr, NN);

    // summary = sigmoid(mean(positive, axis=0))
    summary_partial_k<<<256, 256, 0, stream>>>(outP, acc, NN);
    summary_final_k<<<1, 64, 0, stream>>>(acc, outS, NN);
}

// Round 7
// 380.395 us; speedup vs baseline: 4.2614x; 1.0642x over previous
//
#include <hip/hip_runtime.h>
#include <math.h>

namespace {
constexpr int NN = 100000;   // nodes
constexpr int NE = 1000000;  // edges
constexpr int D  = 64;       // feature dim
constexpr int SCAN_CHUNK = 2048;                 // 256 threads * 8
constexpr int NB = (NN + SCAN_CHUNK - 1) / SCAN_CHUNK;  // 49

constexpr int RPB_LOG = 10;                       // rows per bucket = 1024
constexpr int RPB = 1 << RPB_LOG;
constexpr int NBUK = (NN + RPB - 1) >> RPB_LOG;   // 98 buckets
constexpr int TILE = 2048;                        // edges per bin tile
constexpr int NTILES = (NE + TILE - 1) / TILE;    // 489

using ushort_t = unsigned short;

__device__ inline float bf2f(ushort_t u) {
    return __uint_as_float(((unsigned int)u) << 16);
}
__device__ inline ushort_t f2bf(float f) {   // round-to-nearest-even
    unsigned int x = __float_as_uint(f);
    unsigned int r = (x + 0x7fffu + ((x >> 16) & 1u)) >> 16;
    return (ushort_t)r;
}

__global__ void count_deg_k(const int* __restrict__ rows, int* __restrict__ deg, int e) {
    int i = blockIdx.x * blockDim.x + threadIdx.x;
    if (i < e) atomicAdd(&deg[rows[i]], 1);
}

// ---- 3-phase parallel exclusive scan of deg -> rowstart (dis fused in apply) ----
__global__ void scan_partial_k(const int* __restrict__ deg, int* __restrict__ bsum, int n) {
    int base = blockIdx.x * SCAN_CHUNK + threadIdx.x * 8;
    int s = 0;
#pragma unroll
    for (int j = 0; j < 8; ++j) { int i = base + j; s += (i < n) ? deg[i] : 0; }
    for (int off = 32; off; off >>= 1) s += __shfl_down(s, off);
    __shared__ int ws[4];
    if ((threadIdx.x & 63) == 0) ws[threadIdx.x >> 6] = s;
    __syncthreads();
    if (threadIdx.x == 0) bsum[blockIdx.x] = ws[0] + ws[1] + ws[2] + ws[3];
}

__global__ void scan_bsums_k(const int* __restrict__ bsum, int* __restrict__ bpre, int nb) {
    __shared__ int sm[64];
    int v = ((int)threadIdx.x < nb) ? bsum[threadIdx.x] : 0;
    sm[threadIdx.x] = v;
    __syncthreads();
    for (int off = 1; off < 64; off <<= 1) {
        int t = ((int)threadIdx.x >= off) ? sm[threadIdx.x - off] : 0;
        __syncthreads();
        sm[threadIdx.x] += t;
        __syncthreads();
    }
    if ((int)threadIdx.x < nb) bpre[threadIdx.x] = sm[threadIdx.x] - v;  // exclusive
}

__global__ void scan_apply_k(const int* __restrict__ deg, const int* __restrict__ bpre,
                             int* __restrict__ rowstart, float* __restrict__ dis, int n) {
    int tid = threadIdx.x;
    int base = blockIdx.x * SCAN_CHUNK + tid * 8;
    int v[8]; int s = 0;
#pragma unroll
    for (int j = 0; j < 8; ++j) { int i = base + j; v[j] = (i < n) ? deg[i] : 0; s += v[j]; }
    int lane = tid & 63, wid = tid >> 6;
    int sc = s;
    for (int off = 1; off < 64; off <<= 1) {
        int t = __shfl_up(sc, off);
        if (lane >= off) sc += t;
    }
    __shared__ int wsum[4];
    if (lane == 63) wsum[wid] = sc;
    __syncthreads();
    int wpre = 0;
    for (int w = 0; w < wid; ++w) wpre += wsum[w];
    int run = bpre[blockIdx.x] + wpre + sc - s;  // exclusive prefix of this thread
#pragma unroll
    for (int j = 0; j < 8; ++j) {
        int i = base + j;
        if (i < n) {
            rowstart[i] = run;
            dis[i] = rsqrtf((float)(v[j] + 1));  // +1 self-loop
        }
        run += v[j];
    }
}

// bucket write cursors = rowstart at bucket row boundaries
__global__ void init_sort_k(const int* __restrict__ rowstart, int* __restrict__ bcursor) {
    int t = threadIdx.x;
    if (t < NBUK) bcursor[t] = rowstart[t << RPB_LOG];
}

// Phase A: bin edges into 98 row-range buckets with tile-contiguous chunk
// allocation (dense 64B-line writes; fixes reorder_k's 18x write amplification).
// Payload packed: (r & 1023) << 17 | c   (c < 2^17)
__global__ void bin_k(const int* __restrict__ rows, const int* __restrict__ cols,
                      int* __restrict__ bcursor, unsigned int* __restrict__ binned, int e) {
    __shared__ int hist[NBUK];
    __shared__ int gbase[NBUK];
    __shared__ int lofs[NBUK];
    int base = blockIdx.x * TILE;
    for (int i = threadIdx.x; i < NBUK; i += blockDim.x) { hist[i] = 0; lofs[i] = 0; }
    __syncthreads();
    int r[8], c[8], bk[8];
#pragma unroll
    for (int j = 0; j < 8; ++j) {
        int i = base + j * 256 + threadIdx.x;
        if (i < e) {
            r[j] = rows[i]; c[j] = cols[i];
            bk[j] = r[j] >> RPB_LOG;
            atomicAdd(&hist[bk[j]], 1);
        } else bk[j] = -1;
    }
    __syncthreads();
    if (threadIdx.x < NBUK) {
        int h = hist[threadIdx.x];
        gbase[threadIdx.x] = h ? atomicAdd(&bcursor[threadIdx.x], h) : 0;
    }
    __syncthreads();
#pragma unroll
    for (int j = 0; j < 8; ++j) {
        if (bk[j] >= 0) {
            int l = atomicAdd(&lofs[bk[j]], 1);
            unsigned int v = ((unsigned int)(r[j] & (RPB - 1)) << 17) | (unsigned int)c[j];
            binned[gbase[bk[j]] + l] = v;
        }
    }
}

// Phase B: per-bucket counting sort. One block per bucket; rowstart slice +
// cursors in LDS; writes confined to the bucket's contiguous ~41KB region
// (single-CU locality -> dense L2 writeback).
__global__ void bucket_sort_k(const int* __restrict__ rowstart,
                              const unsigned int* __restrict__ binned,
                              int* __restrict__ scols) {
    __shared__ int srs[RPB];
    __shared__ int lcur[RPB];
    int b = blockIdx.x;
    int row0 = b << RPB_LOG;
    int nrows = min(RPB, NN - row0);
    for (int i = threadIdx.x; i < nrows; i += blockDim.x) {
        srs[i] = rowstart[row0 + i];
        lcur[i] = 0;
    }
    __syncthreads();
    int seg_lo = srs[0];
    int seg_hi = (row0 + nrows < NN) ? rowstart[row0 + nrows] : NE;
    for (int i = seg_lo + (int)threadIdx.x; i < seg_hi; i += (int)blockDim.x) {
        unsigned int v = binned[i];
        int rl = (int)(v >> 17);
        int c  = (int)(v & 0x1FFFFu);
        int pos = srs[rl] + atomicAdd(&lcur[rl], 1);
        scols[pos] = c;
    }
}

// [n,64] @ [64,64] LDS-tiled, register-blocked. 256 thr (16x16), 64 rows/block,
// 4x4 out/thread. NO __launch_bounds__ (64-VGPR cap => accumulator spill, R4).
// Epilogue: outS[r] = bf16(dis[rm]*acc); optionally outU[r] = bf16(acc).
__global__ void gemm64_k(const float* __restrict__ in, const float* __restrict__ W,
                         ushort_t* __restrict__ outS, ushort_t* outU,
                         const float* __restrict__ dis, int n, int nmod) {
    __shared__ float sx[64][68];
    __shared__ float sw[64][64];
    int tid = threadIdx.x;
    const float4* W4 = (const float4*)W;
    float4* sw4 = (float4*)&sw[0][0];
#pragma unroll
    for (int i = 0; i < 4; ++i) sw4[tid + 256 * i] = W4[tid + 256 * i];
    int row0 = blockIdx.x * 64;
    const float4* x4 = (const float4*)(in + (size_t)row0 * D);
#pragma unroll
    for (int ii = 0; ii < 4; ++ii) {
        int i = tid + 256 * ii;
        int r = i >> 4, k4 = i & 15;
        float4 v = (row0 + r < n) ? x4[i] : float4{0.f, 0.f, 0.f, 0.f};
        ((float4*)&sx[r][0])[k4] = v;
    }
    __syncthreads();
    int tx = tid & 15, ty = tid >> 4;
    int c0 = tx * 4, r0 = ty * 4;
    float acc[4][4] = {};
#pragma unroll 4
    for (int kk = 0; kk < 64; kk += 4) {
        float4 b0 = *(const float4*)&sw[kk + 0][c0];
        float4 b1 = *(const float4*)&sw[kk + 1][c0];
        float4 b2 = *(const float4*)&sw[kk + 2][c0];
        float4 b3 = *(const float4*)&sw[kk + 3][c0];
#pragma unroll
        for (int i = 0; i < 4; ++i) {
            float4 a = *(const float4*)&sx[r0 + i][kk];
            acc[i][0] = fmaf(a.x, b0.x, acc[i][0]);
            acc[i][1] = fmaf(a.x, b0.y, acc[i][1]);
            acc[i][2] = fmaf(a.x, b0.z, acc[i][2]);
            acc[i][3] = fmaf(a.x, b0.w, acc[i][3]);
            acc[i][0] = fmaf(a.y, b1.x, acc[i][0]);
            acc[i][1] = fmaf(a.y, b1.y, acc[i][1]);
            acc[i][2] = fmaf(a.y, b1.z, acc[i][2]);
            acc[i][3] = fmaf(a.y, b1.w, acc[i][3]);
            acc[i][0] = fmaf(a.z, b2.x, acc[i][0]);
            acc[i][1] = fmaf(a.z, b2.y, acc[i][1]);
            acc[i][2] = fmaf(a.z, b2.z, acc[i][2]);
            acc[i][3] = fmaf(a.z, b2.w, acc[i][3]);
            acc[i][0] = fmaf(a.w, b3.x, acc[i][0]);
            acc[i][1] = fmaf(a.w, b3.y, acc[i][1]);
            acc[i][2] = fmaf(a.w, b3.z, acc[i][2]);
            acc[i][3] = fmaf(a.w, b3.w, acc[i][3]);
        }
    }
#pragma unroll
    for (int i = 0; i < 4; ++i) {
        int r = row0 + r0 + i;
        if (r < n) {
            int rm = (r >= nmod) ? r - nmod : r;
            float s = dis[rm];
            ushort_t u0[4], u1[4];
#pragma unroll
            for (int j = 0; j < 4; ++j) {
                u0[j] = f2bf(s * acc[i][j]);
                u1[j] = f2bf(acc[i][j]);
            }
            *(uint2*)(outS + (size_t)r * D + c0) = *(uint2*)u0;  // 8B store
            if (outU) *(uint2*)(outU + (size_t)r * D + c0) = *(uint2*)u1;
        }
    }
}

// pxs[r] = dis[r] * xw[perm[r]] — permuted, scaled gather table (bf16)
__global__ void build_perm_k(const ushort_t* __restrict__ xw_bf,
                             ushort_t* __restrict__ pxs,
                             const int* __restrict__ perm,
                             const float* __restrict__ dis, int n) {
    int lane = threadIdx.x & 63;
    int r = blockIdx.x * (blockDim.x >> 6) + (threadIdx.x >> 6);
    if (r >= n) return;
    int pr = perm[r];
    float s = dis[r];
    pxs[(size_t)r * D + lane] = f2bf(s * bf2f(xw_bf[(size_t)pr * D + lane]));
}

// Dual gather-aggregate: one wave per row, lane = feature, P and N branches
// share ONE index stream; norms pre-folded into bf16 tables.
// outX[r] = dis[r]*(sum_j tX[c_j] + tX[r]) + b  (+ optional PReLU)
__global__ void agg_dual_k(const ushort_t* __restrict__ tP, const ushort_t* __restrict__ tN,
                           float* __restrict__ dstP, float* __restrict__ dstN,
                           const float* __restrict__ dis,
                           const int* __restrict__ rowstart, const int* __restrict__ deg,
                           const int* __restrict__ scols,
                           const float* __restrict__ bias, const float* __restrict__ prelu_a,
                           int n) {
    int lane = threadIdx.x & 63;
    int r = blockIdx.x * (blockDim.x >> 6) + (threadIdx.x >> 6);
    if (r >= n) return;
    int rs   = __builtin_amdgcn_readfirstlane(r);
    int base = __builtin_amdgcn_readfirstlane(rowstart[rs]);
    int dg   = __builtin_amdgcn_readfirstlane(deg[rs]);
    float dr = dis[rs];
    float accP = bf2f(tP[(size_t)rs * D + lane]);   // self-loop term
    float accN = bf2f(tN[(size_t)rs * D + lane]);
    int j = 0;
    for (; j + 4 <= dg; j += 4) {
        int c0 = scols[base + j],     c1 = scols[base + j + 1];
        int c2 = scols[base + j + 2], c3 = scols[base + j + 3];
        float p0 = bf2f(tP[(size_t)c0 * D + lane]);
        float p1 = bf2f(tP[(size_t)c1 * D + lane]);
        float p2 = bf2f(tP[(size_t)c2 * D + lane]);
        float p3 = bf2f(tP[(size_t)c3 * D + lane]);
        float q0 = bf2f(tN[(size_t)c0 * D + lane]);
        float q1 = bf2f(tN[(size_t)c1 * D + lane]);
        float q2 = bf2f(tN[(size_t)c2 * D + lane]);
        float q3 = bf2f(tN[(size_t)c3 * D + lane]);
        accP += (p0 + p1) + (p2 + p3);
        accN += (q0 + q1) + (q2 + q3);
    }
    for (; j < dg; ++j) {
        int c = scols[base + j];
        accP += bf2f(tP[(size_t)c * D + lane]);
        accN += bf2f(tN[(size_t)c * D + lane]);
    }
    float b = bias[lane];
    float vP = fmaf(dr, accP, b);
    float vN = fmaf(dr, accN, b);
    if (prelu_a) {
        float a = *prelu_a;
        vP = vP >= 0.f ? vP : a * vP;
        vN = vN >= 0.f ? vN : a * vN;
    }
    dstP[(size_t)rs * D + lane] = vP;
    dstN[(size_t)rs * D + lane] = vN;
}

__global__ void summary_partial_k(const float* __restrict__ pos, float* __restrict__ acc, int n) {
    int lane = threadIdx.x & 63;
    int wave = (blockIdx.x * blockDim.x + threadIdx.x) >> 6;
    int nw = (gridDim.x * blockDim.x) >> 6;
    float s = 0.f;
    for (int r = wave; r < n; r += nw) s += pos[(size_t)r * D + lane];
    atomicAdd(&acc[lane], s);
}

__global__ void summary_final_k(const float* __restrict__ acc, float* __restrict__ out, int n) {
    int f = threadIdx.x;
    if (f < D) {
        float m = acc[f] / (float)n;
        out[f] = 1.f / (1.f + expf(-m));
    }
}
} // namespace

extern "C" void kernel_launch(void* const* d_in, const int* in_sizes, int n_in,
                              void* d_out, int out_size, void* d_ws, size_t ws_size,
                              hipStream_t stream) {
    (void)in_sizes; (void)n_in; (void)out_size; (void)ws_size;
    const float* x       = (const float*)d_in[0];
    const int*   ei      = (const int*)  d_in[1];
    const int*   perm    = (const int*)  d_in[2];
    const float* W1      = (const float*)d_in[3];
    const float* b1      = (const float*)d_in[4];
    const float* prelu_a = (const float*)d_in[5];
    const float* W2      = (const float*)d_in[6];
    const float* b2      = (const float*)d_in[7];

    float* outP = (float*)d_out;
    float* outN = outP + (size_t)NN * D;
    float* outS = outN + (size_t)NN * D;

    const int* erows = ei;
    const int* ecols = ei + NE;

    char* ws = (char*)d_ws;
    size_t off = 0;
    auto alloc = [&](size_t bytes) {
        void* p = ws + off;
        off = (off + bytes + 255) & ~(size_t)255;
        return p;
    };
    int*      deg      = (int*)     alloc((size_t)NN * 4);
    float*    dis      = (float*)   alloc((size_t)NN * 4);
    int*      rowstart = (int*)     alloc((size_t)NN * 4);
    int*      bcursor  = (int*)     alloc((size_t)NBUK * 4);
    int*      bsum     = (int*)     alloc(256);
    int*      bpre     = (int*)     alloc(256);
    unsigned int* binned = (unsigned int*)alloc((size_t)NE * 4);
    int*      scols    = (int*)     alloc((size_t)NE * 4);
    ushort_t* xs       = (ushort_t*)alloc((size_t)NN * D * 2);   // dis-scaled x@W1 (bf16)
    ushort_t* xw_bf    = (ushort_t*)alloc((size_t)NN * D * 2);   // unscaled x@W1 (bf16)
    float*    aggP     = (float*)   alloc((size_t)2 * NN * D * 4); // [aggP | aggN] contiguous
    float*    aggN     = aggP + (size_t)NN * D;
    ushort_t* tP       = (ushort_t*)alloc((size_t)2 * NN * D * 2); // [tP | tN] contiguous (L2 tables)
    ushort_t* tN       = tP + (size_t)NN * D;
    ushort_t* pxs      = tN;    // alias: permuted L1 table lives where tN goes later
    float*    acc      = (float*)   alloc((size_t)D * 4);

    hipMemsetAsync(deg, 0, (size_t)NN * 4, stream);
    hipMemsetAsync(acc, 0, (size_t)D * 4, stream);

    // graph preprocessing (reused by both layers and both branches)
    count_deg_k<<<(NE + 255) / 256, 256, 0, stream>>>(erows, deg, NE);
    scan_partial_k<<<NB, 256, 0, stream>>>(deg, bsum, NN);
    scan_bsums_k<<<1, 64, 0, stream>>>(bsum, bpre, NB);
    scan_apply_k<<<NB, 256, 0, stream>>>(deg, bpre, rowstart, dis, NN);
    init_sort_k<<<1, 128, 0, stream>>>(rowstart, bcursor);
    bin_k<<<NTILES, 256, 0, stream>>>(erows, ecols, bcursor, binned, NE);
    bucket_sort_k<<<NBUK, 1024, 0, stream>>>(rowstart, binned, scols);

    const int aggBlocks = (NN + 3) / 4;

    // layer 1: xs = dis*x@W1 (bf16), xw_bf = x@W1 (bf16); pxs = permuted+scaled
    gemm64_k<<<(NN + 63) / 64, 256, 0, stream>>>(x, W1, xs, xw_bf, dis, NN, NN);
    build_perm_k<<<aggBlocks, 256, 0, stream>>>(xw_bf, pxs, perm, dis, NN);
    agg_dual_k<<<aggBlocks, 256, 0, stream>>>(xs, pxs, aggP, aggN, dis, rowstart, deg,
                                              scols, b1, prelu_a, NN);

    // layer 2: one gemm over [aggP|aggN] (200k rows) -> scaled bf16 tables
    gemm64_k<<<(2 * NN + 63) / 64, 256, 0, stream>>>(aggP, W2, tP, nullptr, dis, 2 * NN, NN);
    agg_dual_k<<<aggBlocks, 256, 0, stream>>>(tP, tN, outP, outN, dis, rowstart, deg,
                                              scols, b2, nullptr, NN);

    // summary = sigmoid(mean(positive, axis=0))
    summary_partial_k<<<256, 256, 0, stream>>>(outP, acc, NN);
    summary_final_k<<<1, 64, 0, stream>>>(acc, outS, NN);
}

// Round 8
// 319.253 us; speedup vs baseline: 5.0775x; 1.1915x over previous
//
#include <hip/hip_runtime.h>
#include <math.h>

namespace {
constexpr int NN = 100000;   // nodes
constexpr int NE = 1000000;  // edges
constexpr int D  = 64;       // feature dim

constexpr int RPB_LOG = 10;                       // rows per bucket = 1024
constexpr int RPB = 1 << RPB_LOG;
constexpr int NBUK = (NN + RPB - 1) >> RPB_LOG;   // 98 buckets
constexpr int CAP = 16384;                        // bucket capacity (mean 10.2K, +61 sigma)
constexpr int TILE = 2048;                        // edges per bin tile
constexpr int NTILES = (NE + TILE - 1) / TILE;    // 489

using ushort_t = unsigned short;

__device__ inline ushort_t f2bf(float f) {   // round-to-nearest-even
    unsigned int x = __float_as_uint(f);
    unsigned int r = (x + 0x7fffu + ((x >> 16) & 1u)) >> 16;
    return (ushort_t)r;
}
__device__ inline float bf_lo(unsigned int v) { return __uint_as_float(v << 16); }
__device__ inline float bf_hi(unsigned int v) { return __uint_as_float(v & 0xffff0000u); }

__global__ void iperm_k(const int* __restrict__ perm, int* __restrict__ iperm, int n) {
    int i = blockIdx.x * blockDim.x + threadIdx.x;
    if (i < n) iperm[perm[i]] = i;
}

// Phase A: bin edges into 98 fixed-capacity row-range buckets with
// tile-contiguous chunk allocation (dense 64B-line writes).
// Payload packed: (r & 1023) << 17 | c   (c < 2^17)
__global__ void bin_k(const int* __restrict__ rows, const int* __restrict__ cols,
                      int* __restrict__ bcount, unsigned int* __restrict__ binned, int e) {
    __shared__ int hist[NBUK];
    __shared__ int gbase[NBUK];
    __shared__ int lofs[NBUK];
    int base = blockIdx.x * TILE;
    for (int i = threadIdx.x; i < NBUK; i += blockDim.x) { hist[i] = 0; lofs[i] = 0; }
    __syncthreads();
    int r[8], c[8], bk[8];
#pragma unroll
    for (int j = 0; j < 8; ++j) {
        int i = base + j * 256 + threadIdx.x;
        if (i < e) {
            r[j] = rows[i]; c[j] = cols[i];
            bk[j] = r[j] >> RPB_LOG;
            atomicAdd(&hist[bk[j]], 1);
        } else bk[j] = -1;
    }
    __syncthreads();
    if (threadIdx.x < NBUK) {
        int h = hist[threadIdx.x];
        gbase[threadIdx.x] = h ? atomicAdd(&bcount[threadIdx.x], h) : 0;
    }
    __syncthreads();
#pragma unroll
    for (int j = 0; j < 8; ++j) {
        if (bk[j] >= 0) {
            int l = gbase[bk[j]] + atomicAdd(&lofs[bk[j]], 1);
            if (l < CAP) {
                unsigned int v = ((unsigned int)(r[j] & (RPB - 1)) << 17) | (unsigned int)c[j];
                binned[(size_t)bk[j] * CAP + l] = v;
            }
        }
    }
}

// exclusive scan of the 98 bucket counts -> bucket bases in scols
__global__ void bucket_base_k(const int* __restrict__ bcount, int* __restrict__ bbase) {
    __shared__ int sm[128];
    int t = threadIdx.x;
    int v = (t < NBUK) ? bcount[t] : 0;
    sm[t] = v;
    __syncthreads();
    for (int off = 1; off < 128; off <<= 1) {
        int u = (t >= off) ? sm[t - off] : 0;
        __syncthreads();
        sm[t] += u;
        __syncthreads();
    }
    if (t < NBUK) bbase[t] = sm[t] - v;  // exclusive
}

// Phase B: per-bucket counting sort + per-row deg/rowstart/dis production.
// One block (1024 thr) per bucket; histogram + block scan in LDS; writes
// confined to the bucket's contiguous region.
__global__ void bucket_sort_k(const unsigned int* __restrict__ binned,
                              const int* __restrict__ bcount, const int* __restrict__ bbase,
                              int* __restrict__ scols, int* __restrict__ rowstart,
                              int* __restrict__ deg, float* __restrict__ dis) {
    __shared__ int lcur[RPB];
    __shared__ int srs[RPB];
    __shared__ int wsum[16];
    int b = blockIdx.x;
    int row0 = b << RPB_LOG;
    int nrows = min(RPB, NN - row0);
    int cnt = bcount[b];
    const unsigned int* src = binned + (size_t)b * CAP;
    int tid = threadIdx.x;
    lcur[tid] = 0;
    __syncthreads();
    for (int i = tid; i < cnt; i += RPB) atomicAdd(&lcur[src[i] >> 17], 1);
    __syncthreads();
    int d = (tid < nrows) ? lcur[tid] : 0;
    // block-wide exclusive scan of d
    int lane = tid & 63, wid = tid >> 6;
    int inc = d;
#pragma unroll
    for (int off = 1; off < 64; off <<= 1) {
        int t = __shfl_up(inc, off);
        if (lane >= off) inc += t;
    }
    if (lane == 63) wsum[wid] = inc;
    __syncthreads();
    int wpre = 0;
    for (int w = 0; w < wid; ++w) wpre += wsum[w];
    int gstart = bbase[b] + wpre + inc - d;   // global exclusive prefix
    if (tid < nrows) {
        rowstart[row0 + tid] = gstart;
        deg[row0 + tid] = d;
        dis[row0 + tid] = rsqrtf((float)(d + 1));  // +1 self-loop
    }
    __syncthreads();                 // lcur histogram no longer needed
    srs[tid] = gstart;
    lcur[tid] = 0;
    __syncthreads();
    for (int i = tid; i < cnt; i += RPB) {
        unsigned int v = src[i];
        int rl = (int)(v >> 17);
        int pos = srs[rl] + atomicAdd(&lcur[rl], 1);
        scols[pos] = (int)(v & 0x1FFFFu);
    }
}

// [n,64] @ [64,64] LDS-tiled, register-blocked. 256 thr (16x16), 64 rows/block,
// 4x4 out/thread. NO __launch_bounds__ (64-VGPR cap => accumulator spill, R4).
// Epilogue writes bf16 into the interleaved dual-table layout tPN (row = 256B:
// [P 64 bf16 | N 64 bf16]).
//   mode 1 (layer 1): P-half dense at r; N-half scattered to q=iperm[r],
//                     scaled by dis[q]  (pxs[q] = dis[q]*xw[perm[q]]).
//   mode 2 (layer 2): rows r<nmod are P (offset 0), rows >=nmod are N
//                     (offset 64), both scaled by dis[rm].
__global__ void gemm64_k(const float* __restrict__ in, const float* __restrict__ W,
                         ushort_t* __restrict__ tPN, const int* __restrict__ iperm,
                         const float* __restrict__ dis, int n, int nmod, int mode) {
    __shared__ float sx[64][68];
    __shared__ float sw[64][64];
    int tid = threadIdx.x;
    const float4* W4 = (const float4*)W;
    float4* sw4 = (float4*)&sw[0][0];
#pragma unroll
    for (int i = 0; i < 4; ++i) sw4[tid + 256 * i] = W4[tid + 256 * i];
    int row0 = blockIdx.x * 64;
    const float4* x4 = (const float4*)(in + (size_t)row0 * D);
#pragma unroll
    for (int ii = 0; ii < 4; ++ii) {
        int i = tid + 256 * ii;
        int r = i >> 4, k4 = i & 15;
        float4 v = (row0 + r < n) ? x4[i] : float4{0.f, 0.f, 0.f, 0.f};
        ((float4*)&sx[r][0])[k4] = v;
    }
    __syncthreads();
    int tx = tid & 15, ty = tid >> 4;
    int c0 = tx * 4, r0 = ty * 4;
    float acc[4][4] = {};
#pragma unroll 4
    for (int kk = 0; kk < 64; kk += 4) {
        float4 b0 = *(const float4*)&sw[kk + 0][c0];
        float4 b1 = *(const float4*)&sw[kk + 1][c0];
        float4 b2 = *(const float4*)&sw[kk + 2][c0];
        float4 b3 = *(const float4*)&sw[kk + 3][c0];
#pragma unroll
        for (int i = 0; i < 4; ++i) {
            float4 a = *(const float4*)&sx[r0 + i][kk];
            acc[i][0] = fmaf(a.x, b0.x, acc[i][0]);
            acc[i][1] = fmaf(a.x, b0.y, acc[i][1]);
            acc[i][2] = fmaf(a.x, b0.z, acc[i][2]);
            acc[i][3] = fmaf(a.x, b0.w, acc[i][3]);
            acc[i][0] = fmaf(a.y, b1.x, acc[i][0]);
            acc[i][1] = fmaf(a.y, b1.y, acc[i][1]);
            acc[i][2] = fmaf(a.y, b1.z, acc[i][2]);
            acc[i][3] = fmaf(a.y, b1.w, acc[i][3]);
            acc[i][0] = fmaf(a.z, b2.x, acc[i][0]);
            acc[i][1] = fmaf(a.z, b2.y, acc[i][1]);
            acc[i][2] = fmaf(a.z, b2.z, acc[i][2]);
            acc[i][3] = fmaf(a.z, b2.w, acc[i][3]);
            acc[i][0] = fmaf(a.w, b3.x, acc[i][0]);
            acc[i][1] = fmaf(a.w, b3.y, acc[i][1]);
            acc[i][2] = fmaf(a.w, b3.z, acc[i][2]);
            acc[i][3] = fmaf(a.w, b3.w, acc[i][3]);
        }
    }
#pragma unroll
    for (int i = 0; i < 4; ++i) {
        int r = row0 + r0 + i;
        if (r >= n) continue;
        if (mode == 1) {
            float sP = dis[r];
            int q = iperm[r];
            float sN = dis[q];
            ushort_t uP[4], uN[4];
#pragma unroll
            for (int j = 0; j < 4; ++j) {
                uP[j] = f2bf(sP * acc[i][j]);
                uN[j] = f2bf(sN * acc[i][j]);
            }
            *(uint2*)(tPN + (size_t)r * 128 + c0)      = *(uint2*)uP;
            *(uint2*)(tPN + (size_t)q * 128 + 64 + c0) = *(uint2*)uN;
        } else {
            int rm  = (r >= nmod) ? r - nmod : r;
            int off = (r >= nmod) ? 64 : 0;
            float s = dis[rm];
            ushort_t u[4];
#pragma unroll
            for (int j = 0; j < 4; ++j) u[j] = f2bf(s * acc[i][j]);
            *(uint2*)(tPN + (size_t)rm * 128 + off + c0) = *(uint2*)u;
        }
    }
}

// Dual gather-aggregate over the interleaved table. One wave per row; lanes
// 0-31 = P half, 32-63 = N half; each lane covers 2 features via one 4B load.
// outX[r] = dis[r]*(sum_j tX[c_j] + tX[r]) + b  (+ optional PReLU)
__global__ void agg_dual_k(const ushort_t* __restrict__ tPN,
                           float* __restrict__ dstP, float* __restrict__ dstN,
                           const float* __restrict__ dis,
                           const int* __restrict__ rowstart, const int* __restrict__ deg,
                           const int* __restrict__ scols,
                           const float* __restrict__ bias, const float* __restrict__ prelu_a,
                           int n) {
    int lane = threadIdx.x & 63;
    int hl = lane & 31, half = lane >> 5;
    int r = blockIdx.x * (blockDim.x >> 6) + (threadIdx.x >> 6);
    if (r >= n) return;
    int rs   = __builtin_amdgcn_readfirstlane(r);
    int base = __builtin_amdgcn_readfirstlane(rowstart[rs]);
    int dg   = __builtin_amdgcn_readfirstlane(deg[rs]);
    float dr = dis[rs];
    size_t lofs = (size_t)(half * 64 + hl * 2);
    unsigned int sv = *(const unsigned int*)(tPN + (size_t)rs * 128 + lofs);
    float a0 = bf_lo(sv), a1 = bf_hi(sv);     // self-loop term
    int j = 0;
    for (; j + 4 <= dg; j += 4) {
        int c0 = scols[base + j],     c1 = scols[base + j + 1];
        int c2 = scols[base + j + 2], c3 = scols[base + j + 3];
        unsigned int v0 = *(const unsigned int*)(tPN + (size_t)c0 * 128 + lofs);
        unsigned int v1 = *(const unsigned int*)(tPN + (size_t)c1 * 128 + lofs);
        unsigned int v2 = *(const unsigned int*)(tPN + (size_t)c2 * 128 + lofs);
        unsigned int v3 = *(const unsigned int*)(tPN + (size_t)c3 * 128 + lofs);
        a0 += bf_lo(v0) + bf_lo(v1) + bf_lo(v2) + bf_lo(v3);
        a1 += bf_hi(v0) + bf_hi(v1) + bf_hi(v2) + bf_hi(v3);
    }
    for (; j < dg; ++j) {
        int c = scols[base + j];
        unsigned int v = *(const unsigned int*)(tPN + (size_t)c * 128 + lofs);
        a0 += bf_lo(v);
        a1 += bf_hi(v);
    }
    float2 bv = *(const float2*)(bias + 2 * hl);
    float v0 = fmaf(dr, a0, bv.x);
    float v1 = fmaf(dr, a1, bv.y);
    if (prelu_a) {
        float a = *prelu_a;
        v0 = v0 >= 0.f ? v0 : a * v0;
        v1 = v1 >= 0.f ? v1 : a * v1;
    }
    float* dst = half ? dstN : dstP;
    *(float2*)(dst + (size_t)rs * D + 2 * hl) = float2{v0, v1};
}

__global__ void summary_partial_k(const float* __restrict__ pos, float* __restrict__ acc, int n) {
    int lane = threadIdx.x & 63;
    int wave = (blockIdx.x * blockDim.x + threadIdx.x) >> 6;
    int nw = (gridDim.x * blockDim.x) >> 6;
    float s = 0.f;
    for (int r = wave; r < n; r += nw) s += pos[(size_t)r * D + lane];
    atomicAdd(&acc[lane], s);
}

__global__ void summary_final_k(const float* __restrict__ acc, float* __restrict__ out, int n) {
    int f = threadIdx.x;
    if (f < D) {
        float m = acc[f] / (float)n;
        out[f] = 1.f / (1.f + expf(-m));
    }
}
} // namespace

extern "C" void kernel_launch(void* const* d_in, const int* in_sizes, int n_in,
                              void* d_out, int out_size, void* d_ws, size_t ws_size,
                              hipStream_t stream) {
    (void)in_sizes; (void)n_in; (void)out_size; (void)ws_size;
    const float* x       = (const float*)d_in[0];
    const int*   ei      = (const int*)  d_in[1];
    const int*   perm    = (const int*)  d_in[2];
    const float* W1      = (const float*)d_in[3];
    const float* b1      = (const float*)d_in[4];
    const float* prelu_a = (const float*)d_in[5];
    const float* W2      = (const float*)d_in[6];
    const float* b2      = (const float*)d_in[7];

    float* outP = (float*)d_out;
    float* outN = outP + (size_t)NN * D;
    float* outS = outN + (size_t)NN * D;

    const int* erows = ei;
    const int* ecols = ei + NE;

    char* ws = (char*)d_ws;
    size_t off = 0;
    auto alloc = [&](size_t bytes) {
        void* p = ws + off;
        off = (off + bytes + 255) & ~(size_t)255;
        return p;
    };
    int*      deg      = (int*)     alloc((size_t)NN * 4);
    float*    dis      = (float*)   alloc((size_t)NN * 4);
    int*      rowstart = (int*)     alloc((size_t)NN * 4);
    int*      iperm    = (int*)     alloc((size_t)NN * 4);
    int*      bcount   = (int*)     alloc((size_t)NBUK * 4);
    int*      bbase    = (int*)     alloc((size_t)NBUK * 4);
    unsigned int* binned = (unsigned int*)alloc((size_t)NBUK * CAP * 4);  // 6.4 MB
    int*      scols    = (int*)     alloc((size_t)NE * 4);
    ushort_t* tPN      = (ushort_t*)alloc((size_t)NN * 128 * 2);  // interleaved dual table, 25.6 MB
    float*    aggPN    = (float*)   alloc((size_t)2 * NN * D * 4); // [aggP | aggN], 51.2 MB
    float*    aggP     = aggPN;
    float*    aggN     = aggPN + (size_t)NN * D;
    float*    acc      = (float*)   alloc((size_t)D * 4);
    // ~90 MB total

    hipMemsetAsync(bcount, 0, (size_t)NBUK * 4, stream);
    hipMemsetAsync(acc, 0, (size_t)D * 4, stream);

    // graph preprocessing: bin -> base scan -> per-bucket sort (+deg/rowstart/dis)
    iperm_k<<<(NN + 255) / 256, 256, 0, stream>>>(perm, iperm, NN);
    bin_k<<<NTILES, 256, 0, stream>>>(erows, ecols, bcount, binned, NE);
    bucket_base_k<<<1, 128, 0, stream>>>(bcount, bbase);
    bucket_sort_k<<<NBUK, RPB, 0, stream>>>(binned, bcount, bbase, scols, rowstart, deg, dis);

    const int aggBlocks = (NN + 3) / 4;

    // layer 1: tPN[c] = [dis[c]*xw[c] | dis[c]*xw[perm[c]]]  (one gemm, fused scatter)
    gemm64_k<<<(NN + 63) / 64, 256, 0, stream>>>(x, W1, tPN, iperm, dis, NN, NN, 1);
    agg_dual_k<<<aggBlocks, 256, 0, stream>>>(tPN, aggP, aggN, dis, rowstart, deg,
                                              scols, b1, prelu_a, NN);

    // layer 2: one gemm over [aggP|aggN] (200k rows) -> interleaved scaled table
    gemm64_k<<<(2 * NN + 63) / 64, 256, 0, stream>>>(aggPN, W2, tPN, nullptr, dis, 2 * NN, NN, 2);
    agg_dual_k<<<aggBlocks, 256, 0, stream>>>(tPN, outP, outN, dis, rowstart, deg,
                                              scols, b2, nullptr, NN);

    // summary = sigmoid(mean(positive, axis=0))
    summary_partial_k<<<256, 256, 0, stream>>>(outP, acc, NN);
    summary_final_k<<<1, 64, 0, stream>>>(acc, outS, NN);
}